// Round 3
// baseline (215.561 us; speedup 1.0000x reference)
//
#include <hip/hip_runtime.h>

// LSTM: B=32768, T=28, D=28, H=8, gates=32, classes=10.
// 16 lanes per batch element; lane p owns gate columns {p, 16+p} of W
// (72 fp32 values, asm-pinned into VGPRs so the RA cannot rematerialize
// the loads inside the t-loop). p<8 owns (i_p, f_p); p=8+u owns (j_u, o_u).
// One shfl_xor(8) exchanges gate pairs; 8 shfl broadcasts rebuild h[8].
// 2048 blocks x 256 threads = 8192 waves; VGPR<=128 -> 4 waves/SIMD.

#define TSTEPS 28
#define DIN    28
#define NH     8
#define NG     32   // 4*NH
#define NC     10
#define NROWS  36   // DIN + NH

__device__ __forceinline__ float fast_exp2(float x) {
    return __builtin_amdgcn_exp2f(x);
}
__device__ __forceinline__ float fast_rcp(float x) {
    return __builtin_amdgcn_rcpf(x);
}
__device__ __forceinline__ float fast_sigmoid(float z) {
    return fast_rcp(1.0f + fast_exp2(-1.4426950408889634f * z));
}
__device__ __forceinline__ float fast_tanh(float z) {
    return 1.0f - 2.0f * fast_rcp(1.0f + fast_exp2(2.8853900817779268f * z));
}

__global__ __launch_bounds__(256, 4) void lstm_kernel(
    const float* __restrict__ x,      // [B, T, D]
    const float* __restrict__ W,      // [36, 32]  col order i,j,f,o
    const float* __restrict__ bias,   // [32]
    const float* __restrict__ Wout,   // [8, 10]
    const float* __restrict__ bout,   // [10]
    float* __restrict__ out)          // [B, 10]
{
    const int tid    = blockIdx.x * 256 + threadIdx.x;
    const int e      = tid >> 4;           // batch element
    const int p      = tid & 15;           // gate-column owner within element
    const int lane   = threadIdx.x & 63;
    const int base16 = lane & 48;          // first lane of this element's group
    const bool low   = (p < NH);           // owns (i,f) vs (j,o)

    const float* xb = x + (size_t)e * (TSTEPS * DIN);

    // Preload this lane's 2 gate columns of W (rows 0..35), then pin them in
    // VGPRs: the empty asm is opaque, so the RA can't re-load W in the t-loop.
    float Wr0[NROWS], Wr1[NROWS];
#pragma unroll
    for (int k = 0; k < NROWS; ++k) {
        Wr0[k] = W[k * NG + p];
        Wr1[k] = W[k * NG + 16 + p];
    }
#pragma unroll
    for (int k = 0; k < NROWS; ++k) {
        asm volatile("" : "+v"(Wr0[k]), "+v"(Wr1[k]));
    }

    float bg0 = bias[p];
    float bg1 = bias[16 + p];

    float c = 0.0f;
    float hall[NH];
#pragma unroll
    for (int j = 0; j < NH; ++j) hall[j] = 0.0f;

#pragma unroll 1
    for (int t = 0; t < TSTEPS; ++t) {
        // x row: 7 aligned float4 (row stride 112 B = 7*16 -> always aligned);
        // all 16 lanes of a group read identical addresses -> broadcast.
        float4 xq[7];
        {
            const float4* xv = (const float4*)(xb + t * DIN);
#pragma unroll
            for (int i = 0; i < 7; ++i) xq[i] = xv[i];
        }

        float g0 = bg0, g1 = bg1;

        // x part: 56 FMA, all-register operands
#pragma unroll
        for (int i = 0; i < 7; ++i) {
            g0 = fmaf(xq[i].x, Wr0[4*i+0], g0);  g1 = fmaf(xq[i].x, Wr1[4*i+0], g1);
            g0 = fmaf(xq[i].y, Wr0[4*i+1], g0);  g1 = fmaf(xq[i].y, Wr1[4*i+1], g1);
            g0 = fmaf(xq[i].z, Wr0[4*i+2], g0);  g1 = fmaf(xq[i].z, Wr1[4*i+2], g1);
            g0 = fmaf(xq[i].w, Wr0[4*i+3], g0);  g1 = fmaf(xq[i].w, Wr1[4*i+3], g1);
        }
        // h part: 16 FMA
#pragma unroll
        for (int k = 0; k < NH; ++k) {
            g0 = fmaf(hall[k], Wr0[DIN + k], g0);
            g1 = fmaf(hall[k], Wr1[DIN + k], g1);
        }

        // Pair exchange: lane p<8 has (i_u,f_u), lane 8+u has (j_u,o_u), u=p&7
        float pg0 = __shfl_xor(g0, 8);
        float pg1 = __shfl_xor(g1, 8);
        float ig = low ? g0 : pg0;
        float fg = low ? g1 : pg1;
        float jg = low ? pg0 : g0;
        float og = low ? pg1 : g1;

        // Cell update (gate order i, j, f, o; forget bias 1.0). Both lanes of
        // a pair compute identically -> c stays consistent, no divergence.
        c = c * fast_sigmoid(fg + 1.0f) + fast_sigmoid(ig) * fast_tanh(jg);
        float hu = fast_tanh(c) * fast_sigmoid(og);

        // Broadcast h[0..7] from lanes base16+0..7 (the low-half lanes)
#pragma unroll
        for (int j = 0; j < NH; ++j)
            hall[j] = __shfl(hu, base16 + j, 64);
    }

    // logits = h @ Wout + bout; lanes 0..9 write one column each
    if (p < NC) {
        float acc = bout[p];
#pragma unroll
        for (int k = 0; k < NH; ++k)
            acc = fmaf(hall[k], Wout[k * NC + p], acc);
        out[(size_t)e * NC + p] = acc;
    }
}

extern "C" void kernel_launch(void* const* d_in, const int* in_sizes, int n_in,
                              void* d_out, int out_size, void* d_ws, size_t ws_size,
                              hipStream_t stream) {
    const float* x    = (const float*)d_in[0];
    const float* W    = (const float*)d_in[1];
    const float* b    = (const float*)d_in[2];
    const float* Wout = (const float*)d_in[3];
    const float* bout = (const float*)d_in[4];
    float* out = (float*)d_out;

    const int B = in_sizes[0] / (TSTEPS * DIN);  // 32768
    const int threads = B * 16;                  // 524288
    const int block = 256;
    const int grid = threads / block;            // 2048
    lstm_kernel<<<grid, block, 0, stream>>>(x, W, b, Wout, bout, out);
}

// Round 4
// 179.008 us; speedup vs baseline: 1.2042x; 1.2042x over previous
//
#include <hip/hip_runtime.h>

// LSTM: B=32768, T=28, D=28, H=8, gates=32, classes=10.
// 8 lanes per batch element; lane u owns hidden unit u's 4 gate columns
// (i,j,f,o) of W = 144 fp32 values held in VGPRs. An opaque (non-volatile)
// asm barrier after the preload makes rematerialization of the W loads
// impossible; __launch_bounds__(256,2) gives a 256-VGPR budget so the RA
// has no pressure reason to spill (~235 live).
// x is double-buffered (float4[2][7]) with one-step prefetch.
// 1024 blocks x 256 threads = 4096 waves = 4 waves/SIMD of work.

#define TSTEPS 28
#define DIN    28
#define NH     8
#define NG     32   // 4*NH
#define NC     10
#define NROWS  36   // DIN + NH

__device__ __forceinline__ float fast_exp2(float x) {
    return __builtin_amdgcn_exp2f(x);
}
__device__ __forceinline__ float fast_rcp(float x) {
    return __builtin_amdgcn_rcpf(x);
}
__device__ __forceinline__ float fast_sigmoid(float z) {
    return fast_rcp(1.0f + fast_exp2(-1.4426950408889634f * z));
}
__device__ __forceinline__ float fast_tanh(float z) {
    return 1.0f - 2.0f * fast_rcp(1.0f + fast_exp2(2.8853900817779268f * z));
}

__global__ __launch_bounds__(256, 2) void lstm_kernel(
    const float* __restrict__ x,      // [B, T, D]
    const float* __restrict__ W,      // [36, 32]  col order i,j,f,o
    const float* __restrict__ bias,   // [32]
    const float* __restrict__ Wout,   // [8, 10]
    const float* __restrict__ bout,   // [10]
    float* __restrict__ out)          // [B, 10]
{
    const int tid   = blockIdx.x * 256 + threadIdx.x;
    const int e     = tid >> 3;            // batch element
    const int u     = tid & 7;             // hidden unit owned by this lane
    const int base8 = (threadIdx.x & 63) & ~7;

    const float* xb = x + (size_t)e * (TSTEPS * DIN);

    // ---- Preload this lane's 144 W values, then make them opaque ----
    float Wr[NROWS][4];
#pragma unroll
    for (int k = 0; k < NROWS; ++k) {
#pragma unroll
        for (int gt = 0; gt < 4; ++gt)
            Wr[k][gt] = W[k * NG + gt * NH + u];
    }
#pragma unroll
    for (int k = 0; k < NROWS; ++k) {
        asm("" : "+v"(Wr[k][0]), "+v"(Wr[k][1]),
                 "+v"(Wr[k][2]), "+v"(Wr[k][3]));
    }

    float bg[4];
#pragma unroll
    for (int gt = 0; gt < 4; ++gt) bg[gt] = bias[gt * NH + u];

    float c = 0.0f;
    float hall[NH];
#pragma unroll
    for (int j = 0; j < NH; ++j) hall[j] = 0.0f;

    // ---- x double buffer: row stride 112 B = 7 aligned float4 ----
    float4 xq[2][7];
    {
        const float4* xv = (const float4*)xb;
#pragma unroll
        for (int i = 0; i < 7; ++i) xq[0][i] = xv[i];
    }

    auto do_step = [&](float4 (&cur)[7], float4 (&nxt)[7], int tnext) {
        // Prefetch next step's x first so the loads overlap this step's FMAs.
        if (tnext < TSTEPS) {
            const float4* xv = (const float4*)(xb + tnext * DIN);
#pragma unroll
            for (int i = 0; i < 7; ++i) nxt[i] = xv[i];
        }

        float g[4];
#pragma unroll
        for (int gt = 0; gt < 4; ++gt) g[gt] = bg[gt];

        // x part: 112 FMA, all-register operands (4 independent acc chains)
#pragma unroll
        for (int i = 0; i < 7; ++i) {
#pragma unroll
            for (int gt = 0; gt < 4; ++gt) {
                g[gt] = fmaf(cur[i].x, Wr[4*i+0][gt], g[gt]);
                g[gt] = fmaf(cur[i].y, Wr[4*i+1][gt], g[gt]);
                g[gt] = fmaf(cur[i].z, Wr[4*i+2][gt], g[gt]);
                g[gt] = fmaf(cur[i].w, Wr[4*i+3][gt], g[gt]);
            }
        }
        // h part: 32 FMA
#pragma unroll
        for (int k = 0; k < NH; ++k) {
#pragma unroll
            for (int gt = 0; gt < 4; ++gt)
                g[gt] = fmaf(hall[k], Wr[DIN + k][gt], g[gt]);
        }

        // Cell update (gate order i, j, f, o; forget bias 1.0)
        float ig = fast_sigmoid(g[0]);
        float jg = fast_tanh(g[1]);
        float fg = fast_sigmoid(g[2] + 1.0f);
        float og = fast_sigmoid(g[3]);
        c = c * fg + ig * jg;
        float hu = fast_tanh(c) * og;

        // Broadcast all 8 units' new h across the 8-lane group
#pragma unroll
        for (int j = 0; j < NH; ++j)
            hall[j] = __shfl(hu, base8 + j, 64);
    };

#pragma unroll 1
    for (int tt = 0; tt < TSTEPS; tt += 2) {
        do_step(xq[0], xq[1], tt + 1);
        do_step(xq[1], xq[0], tt + 2);
    }

    // logits = h @ Wout + bout; lane u writes column u, lanes 0-1 also 8+u
    float acc = bout[u];
#pragma unroll
    for (int k = 0; k < NH; ++k)
        acc = fmaf(hall[k], Wout[k * NC + u], acc);
    out[(size_t)e * NC + u] = acc;

    if (u < 2) {
        float acc1 = bout[NH + u];
#pragma unroll
        for (int k = 0; k < NH; ++k)
            acc1 = fmaf(hall[k], Wout[k * NC + NH + u], acc1);
        out[(size_t)e * NC + NH + u] = acc1;
    }
}

extern "C" void kernel_launch(void* const* d_in, const int* in_sizes, int n_in,
                              void* d_out, int out_size, void* d_ws, size_t ws_size,
                              hipStream_t stream) {
    const float* x    = (const float*)d_in[0];
    const float* W    = (const float*)d_in[1];
    const float* b    = (const float*)d_in[2];
    const float* Wout = (const float*)d_in[3];
    const float* bout = (const float*)d_in[4];
    float* out = (float*)d_out;

    const int B = in_sizes[0] / (TSTEPS * DIN);  // 32768
    const int threads = B * NH;                  // 262144
    const int block = 256;
    const int grid = threads / block;            // 1024
    lstm_kernel<<<grid, block, 0, stream>>>(x, W, b, Wout, bout, out);
}